// Round 5
// baseline (302.792 us; speedup 1.0000x reference)
//
#include <hip/hip_runtime.h>
#include <hip/hip_bf16.h>
#include <cstdint>

// Problem constants
#define BB   16
#define PP   1024
#define EE   768
#define HID  768
#define NH   12
#define DH   64
#define NPB  (PP * EE)          // 786432 elements per batch
#define MROWS (BB * PP)         // 16384

typedef __bf16 bf16_t;
typedef __bf16 bf16x8 __attribute__((ext_vector_type(8)));
typedef float  f32x4  __attribute__((ext_vector_type(4)));

// Async global->LDS 16B DMA. LDS dest must be wave-uniform base + lane*16.
__device__ __forceinline__ void gld16(const void* g, void* l) {
    __builtin_amdgcn_global_load_lds(
        (const __attribute__((address_space(1))) void*)(uintptr_t)g,
        (__attribute__((address_space(3))) void*)(uint32_t)(uintptr_t)l,
        16, 0, 0);
}

// ---------------------------------------------------------------------------
// Stage 1: per-slice partial sums for batch-global LayerNorm stats
// ---------------------------------------------------------------------------
__global__ __launch_bounds__(256) void stats1_kernel(const float* __restrict__ x,
                                                     float* __restrict__ part) {
    int bid = blockIdx.x;
    int b = bid >> 6, s = bid & 63;
    const float4* xp = (const float4*)(x + (size_t)b * NPB + (size_t)s * 12288);
    float sum = 0.f, ss = 0.f;
#pragma unroll
    for (int i = 0; i < 12; ++i) {
        float4 v = xp[i * 256 + threadIdx.x];
        sum += v.x + v.y + v.z + v.w;
        ss  += v.x * v.x + v.y * v.y + v.z * v.z + v.w * v.w;
    }
#pragma unroll
    for (int off = 32; off > 0; off >>= 1) {
        sum += __shfl_down(sum, off, 64);
        ss  += __shfl_down(ss,  off, 64);
    }
    __shared__ float tmp[8];
    int wave = threadIdx.x >> 6, lane = threadIdx.x & 63;
    if (lane == 0) { tmp[wave * 2] = sum; tmp[wave * 2 + 1] = ss; }
    __syncthreads();
    if (threadIdx.x == 0) {
        part[bid * 2]     = tmp[0] + tmp[2] + tmp[4] + tmp[6];
        part[bid * 2 + 1] = tmp[1] + tmp[3] + tmp[5] + tmp[7];
    }
}

// ---------------------------------------------------------------------------
// prep: LDS-tiled coalesced weight transposes (fp32 -> bf16) + stats2.
// blocks [0,432): qkvw 64x64 tiles; [432,576): linw tiles; 576: stats.
// ---------------------------------------------------------------------------
__global__ __launch_bounds__(256) void prep_kernel(const float* __restrict__ qkvw,
                                                   const float* __restrict__ linw,
                                                   const float* __restrict__ part,
                                                   bf16_t* __restrict__ qkvT,
                                                   bf16_t* __restrict__ lwT,
                                                   float* __restrict__ stats) {
    int bid = blockIdx.x;
    if (bid < 576) {
        const float* src; bf16_t* dst; int R, C, tr, tc;
        if (bid < 432) { src = qkvw; dst = qkvT; R = 768; C = 2304; tr = bid / 36; tc = bid % 36; }
        else { int i2 = bid - 432; src = linw; dst = lwT; R = 768; C = 768; tr = i2 / 12; tc = i2 % 12; }
        __shared__ bf16_t Ls[64 * 72];
        const int r0 = tr * 64, c0 = tc * 64;
        const int t = threadIdx.x;
#pragma unroll
        for (int it = 0; it < 4; ++it) {
            int idx = it * 256 + t;
            int r = idx >> 4, cq = idx & 15;
            float4 v = *(const float4*)(src + (size_t)(r0 + r) * C + c0 + cq * 4);
            float vv[4] = {v.x, v.y, v.z, v.w};
#pragma unroll
            for (int j = 0; j < 4; ++j) {
                int c = cq * 4 + j;
                Ls[c * 72 + (((r >> 3) ^ (c & 7)) << 3) + (r & 7)] = (bf16_t)vv[j];
            }
        }
        __syncthreads();
#pragma unroll
        for (int it = 0; it < 2; ++it) {
            int idx = it * 256 + t;
            int c = idx >> 3, rq = idx & 7;
            bf16x8 val = *(const bf16x8*)(Ls + c * 72 + ((rq ^ (c & 7)) << 3));
            *(bf16x8*)(dst + (size_t)(c0 + c) * R + r0 + rq * 8) = val;
        }
    } else {
        int wave = threadIdx.x >> 6, lane = threadIdx.x & 63;
#pragma unroll
        for (int j = 0; j < 4; ++j) {
            int b = wave * 4 + j;
            float sum = part[(b * 64 + lane) * 2];
            float ss  = part[(b * 64 + lane) * 2 + 1];
#pragma unroll
            for (int off = 32; off > 0; off >>= 1) {
                sum += __shfl_down(sum, off, 64);
                ss  += __shfl_down(ss,  off, 64);
            }
            if (lane == 0) {
                const float inv_n = 1.f / (float)NPB;
                float mean = sum * inv_n;
                float var  = ss * inv_n - mean * mean;
                stats[b * 2]     = mean;
                stats[b * 2 + 1] = rsqrtf(var + 1e-5f);
            }
        }
    }
}

__global__ __launch_bounds__(256) void ln_apply_kernel(const float* __restrict__ x,
                                                       const float* __restrict__ lnw,
                                                       const float* __restrict__ lnb,
                                                       const float* __restrict__ stats,
                                                       bf16_t* __restrict__ xn) {
    int i = (blockIdx.x * 256 + threadIdx.x) * 8;
    int b = i / NPB;
    int r = i - b * NPB;
    float mean = stats[b * 2], rstd = stats[b * 2 + 1];
    float4 x0 = *(const float4*)(x + i),     x1 = *(const float4*)(x + i + 4);
    float4 w0 = *(const float4*)(lnw + r),   w1 = *(const float4*)(lnw + r + 4);
    float4 c0 = *(const float4*)(lnb + r),   c1 = *(const float4*)(lnb + r + 4);
    union { bf16_t h[8]; uint4 u; } o;
    o.h[0] = (bf16_t)((x0.x - mean) * rstd * w0.x + c0.x);
    o.h[1] = (bf16_t)((x0.y - mean) * rstd * w0.y + c0.y);
    o.h[2] = (bf16_t)((x0.z - mean) * rstd * w0.z + c0.z);
    o.h[3] = (bf16_t)((x0.w - mean) * rstd * w0.w + c0.w);
    o.h[4] = (bf16_t)((x1.x - mean) * rstd * w1.x + c1.x);
    o.h[5] = (bf16_t)((x1.y - mean) * rstd * w1.y + c1.y);
    o.h[6] = (bf16_t)((x1.z - mean) * rstd * w1.z + c1.z);
    o.h[7] = (bf16_t)((x1.w - mean) * rstd * w1.w + c1.w);
    *(uint4*)(xn + i) = o.u;
}

// ---------------------------------------------------------------------------
// Core 256x128 GEMM tile, 512 threads (8 waves, 4m x 2n; each wave 64x64).
// BK=64, DMA staging: As 32KB + Bs 16KB. Chunk slot s = (logical+(row&7))&7.
// ---------------------------------------------------------------------------
template <int KDIM>
__device__ __forceinline__ void gemm_core_256(const bf16_t* __restrict__ A,
                                              const bf16_t* __restrict__ Bt,
                                              int mBase, int nBase,
                                              f32x4 acc[4][4],
                                              bf16_t* As, bf16_t* Bs) {
    const int t = threadIdx.x;             // 0..511
    const int lane = t & 63, wave = t >> 6;
    const int wm = wave >> 1, wn = wave & 1;
    const int m16 = lane & 15, quad = lane >> 4;

    const int sr = t >> 3, s8 = t & 7;
    const bf16_t* pa[4]; const bf16_t* pb[2];
#pragma unroll
    for (int i = 0; i < 4; ++i) {
        int row = i * 64 + sr;
        int g = (s8 - (row & 7)) & 7;
        pa[i] = A + (size_t)(mBase + row) * KDIM + g * 8;
    }
#pragma unroll
    for (int i = 0; i < 2; ++i) {
        int row = i * 64 + sr;
        int g = (s8 - (row & 7)) & 7;
        pb[i] = Bt + (size_t)(nBase + row) * KDIM + g * 8;
    }

    int raOff[4][2], rbOff[4][2];
#pragma unroll
    for (int i = 0; i < 4; ++i) {
        int ra = wm * 64 + i * 16 + m16;
        int rb = wn * 64 + i * 16 + m16;
#pragma unroll
        for (int ks = 0; ks < 2; ++ks) {
            raOff[i][ks] = ra * 64 + (((ks * 4 + quad) + (ra & 7)) & 7) * 8;
            rbOff[i][ks] = rb * 64 + (((ks * 4 + quad) + (rb & 7)) & 7) * 8;
        }
    }

    const f32x4 z = {0.f, 0.f, 0.f, 0.f};
#pragma unroll
    for (int mm = 0; mm < 4; ++mm)
#pragma unroll
        for (int nn = 0; nn < 4; ++nn) acc[mm][nn] = z;

    for (int k0 = 0; k0 < KDIM; k0 += 64) {
        __syncthreads();
#pragma unroll
        for (int i = 0; i < 4; ++i) gld16(pa[i] + k0, As + i * 4096 + t * 8);
#pragma unroll
        for (int i = 0; i < 2; ++i) gld16(pb[i] + k0, Bs + i * 4096 + t * 8);
        __syncthreads();
#pragma unroll
        for (int ks = 0; ks < 2; ++ks) {
            bf16x8 af[4], bfv[4];
#pragma unroll
            for (int i = 0; i < 4; ++i) {
                af[i]  = *(const bf16x8*)(As + raOff[i][ks]);
                bfv[i] = *(const bf16x8*)(Bs + rbOff[i][ks]);
            }
#pragma unroll
            for (int mm = 0; mm < 4; ++mm)
#pragma unroll
                for (int nn = 0; nn < 4; ++nn)
                    acc[mm][nn] = __builtin_amdgcn_mfma_f32_16x16x32_bf16(
                        af[mm], bfv[nn], acc[mm][nn], 0, 0, 0);
        }
    }
}

// ---------------------------------------------------------------------------
// GEMM1: proj = xn @ qkv. 256x128 tiles, grid (18, 64), 512 thr.
// q row-major (B,P,HID); k,v transposed (B,H,DH,P) via in-LDS transpose.
// All global stores 16B.
// ---------------------------------------------------------------------------
__global__ __launch_bounds__(512) void gemm_qkv_kernel(const bf16_t* __restrict__ xn,
                                                       const bf16_t* __restrict__ qkvT,
                                                       bf16_t* __restrict__ q,
                                                       bf16_t* __restrict__ kt,
                                                       bf16_t* __restrict__ vt) {
    __shared__ bf16_t smem[24576];   // 48 KB: core As(16384)+Bs(8192); epilogue reuse
    f32x4 acc[4][4];
    const int mBase = blockIdx.y * 256, nBase = blockIdx.x * 128;
    gemm_core_256<768>(xn, qkvT, mBase, nBase, acc, smem, smem + 16384);

    const int t = threadIdx.x;
    const int lane = t & 63, wave = t >> 6;
    const int wm = wave >> 1, wn = wave & 1;
    const int m16 = lane & 15, quad = lane >> 4;
    const int b = mBase >> 10, p0 = mBase & 1023;

#pragma unroll
    for (int half = 0; half < 2; ++half) {
        const int g = blockIdx.x * 2 + half;
        const int cls = g % 3, h = g / 3;
        const size_t bh = (size_t)(b * NH + h);
        __syncthreads();   // prior phase LDS reads done
        if (cls == 0) {
            // ---- q: row-major into (B,P,HID), LDS 256x72 ----
            if (wn == half) {
#pragma unroll
                for (int mm = 0; mm < 4; ++mm)
#pragma unroll
                    for (int nn = 0; nn < 4; ++nn)
#pragma unroll
                        for (int i = 0; i < 4; ++i)
                            smem[(wm * 64 + mm * 16 + quad * 4 + i) * 72 + nn * 16 + m16] =
                                (bf16_t)acc[mm][nn][i];
            }
            __syncthreads();
#pragma unroll
            for (int it = 0; it < 4; ++it) {
                int slot = it * 512 + t;
                int r = slot >> 3, cc = slot & 7;
                bf16x8 val = *(const bf16x8*)(smem + r * 72 + cc * 8);
                *(bf16x8*)(q + ((size_t)(b * PP + p0 + r)) * HID + h * DH + cc * 8) = val;
            }
        } else {
            // ---- k/v: transposed via LDS T[c][r], 64x264 ----
            bf16_t* dst = (cls == 1) ? kt : vt;
            if (wn == half) {
#pragma unroll
                for (int mm = 0; mm < 4; ++mm)
#pragma unroll
                    for (int nn = 0; nn < 4; ++nn) {
                        int c = nn * 16 + m16;
                        int r0 = wm * 64 + mm * 16 + quad * 4;
                        union { bf16_t hh[4]; uint2 u; } pk;
#pragma unroll
                        for (int i = 0; i < 4; ++i) pk.hh[i] = (bf16_t)acc[mm][nn][i];
                        *(uint2*)(&smem[c * 264 + r0]) = pk.u;
                    }
            }
            __syncthreads();
#pragma unroll
            for (int it = 0; it < 4; ++it) {
                int slot = it * 512 + t;
                int d = slot >> 5, pc = slot & 31;
                bf16x8 val = *(const bf16x8*)(smem + d * 264 + pc * 8);
                *(bf16x8*)(dst + (bh * DH + d) * PP + p0 + pc * 8) = val;
            }
        }
    }
}

// ---------------------------------------------------------------------------
// T_h = K^T V per head (associativity, no softmax). Split-K over 4 waves,
// fp32 LDS reduce, bf16 hi/lo out. grid (192), 256 thr.
// ---------------------------------------------------------------------------
__global__ __launch_bounds__(256) void kv_kernel(const bf16_t* __restrict__ kt,
                                                 const bf16_t* __restrict__ vt,
                                                 bf16_t* __restrict__ thi,
                                                 bf16_t* __restrict__ tlo) {
    __shared__ float red[4 * 64 * 65];   // 66.6 KB
    const int bh = blockIdx.x;
    const bf16_t* Kb = kt + (size_t)bh * DH * PP;
    const bf16_t* Vb = vt + (size_t)bh * DH * PP;
    const int t = threadIdx.x;
    const int lane = t & 63, wave = t >> 6;
    const int m16 = lane & 15, quad = lane >> 4;
    const f32x4 z = {0.f, 0.f, 0.f, 0.f};
    f32x4 acc[4][4];
#pragma unroll
    for (int mm = 0; mm < 4; ++mm)
#pragma unroll
        for (int nn = 0; nn < 4; ++nn) acc[mm][nn] = z;

    for (int ks = 0; ks < 8; ++ks) {
        int kb = wave * 256 + ks * 32 + quad * 8;
        bf16x8 af[4], bfv[4];
#pragma unroll
        for (int mm = 0; mm < 4; ++mm)
            af[mm] = *(const bf16x8*)(Kb + (size_t)(mm * 16 + m16) * PP + kb);
#pragma unroll
        for (int nn = 0; nn < 4; ++nn)
            bfv[nn] = *(const bf16x8*)(Vb + (size_t)(nn * 16 + m16) * PP + kb);
#pragma unroll
        for (int mm = 0; mm < 4; ++mm)
#pragma unroll
            for (int nn = 0; nn < 4; ++nn)
                acc[mm][nn] = __builtin_amdgcn_mfma_f32_16x16x32_bf16(
                    af[mm], bfv[nn], acc[mm][nn], 0, 0, 0);
    }
#pragma unroll
    for (int mm = 0; mm < 4; ++mm)
#pragma unroll
        for (int nn = 0; nn < 4; ++nn)
#pragma unroll
            for (int i = 0; i < 4; ++i)
                red[wave * 4160 + (mm * 16 + quad * 4 + i) * 65 + nn * 16 + m16] =
                    acc[mm][nn][i];
    __syncthreads();
#pragma unroll
    for (int j = 0; j < 16; ++j) {
        int idx = j * 256 + t;            // = d1*64 + d2
        int m = idx >> 6, n = idx & 63;
        int a = m * 65 + n;
        float s = red[a] + red[4160 + a] + red[8320 + a] + red[12480 + a];
        bf16_t hi = (bf16_t)s;
        float lo = s - (float)hi;
        thi[(size_t)bh * 4096 + idx] = hi;
        tlo[(size_t)bh * 4096 + idx] = (bf16_t)lo;
    }
}

// ---------------------------------------------------------------------------
// U^b[h*64+d1][e] = sum_d2 T_h[d1][d2] * lin_w[h*64+d2][e], stored transposed
// as Ut[b][e][h*64+d1] (Bt operand of final GEMM). grid (192, 3), 256 thr.
// ---------------------------------------------------------------------------
__global__ __launch_bounds__(256) void u_kernel(const bf16_t* __restrict__ thi,
                                                const bf16_t* __restrict__ tlo,
                                                const bf16_t* __restrict__ lwT,
                                                bf16_t* __restrict__ ut) {
    const int bh = blockIdx.x;
    const int b = bh / NH, h = bh - b * NH;
    const int nBase = blockIdx.y * 256;
    const bf16_t* Th = thi + (size_t)bh * 4096;
    const bf16_t* Tl = tlo + (size_t)bh * 4096;
    const int t = threadIdx.x, lane = t & 63, wave = t >> 6;
    const int wm = wave >> 1, wn = wave & 1;
    const int m16 = lane & 15, quad = lane >> 4;
    const f32x4 z = {0.f, 0.f, 0.f, 0.f};
    f32x4 acc[2][8];
#pragma unroll
    for (int mm = 0; mm < 2; ++mm)
#pragma unroll
        for (int nn = 0; nn < 8; ++nn) acc[mm][nn] = z;

#pragma unroll
    for (int ks = 0; ks < 2; ++ks) {
        bf16x8 ah[2], al[2], bfr[8];
#pragma unroll
        for (int mm = 0; mm < 2; ++mm) {
            ah[mm] = *(const bf16x8*)(Th + (wm * 32 + mm * 16 + m16) * 64 + ks * 32 + quad * 8);
            al[mm] = *(const bf16x8*)(Tl + (wm * 32 + mm * 16 + m16) * 64 + ks * 32 + quad * 8);
        }
#pragma unroll
        for (int nn = 0; nn < 8; ++nn)
            bfr[nn] = *(const bf16x8*)(
                lwT + (size_t)(nBase + wn * 128 + nn * 16 + m16) * 768 + h * 64 + ks * 32 + quad * 8);
#pragma unroll
        for (int mm = 0; mm < 2; ++mm)
#pragma unroll
            for (int nn = 0; nn < 8; ++nn) {
                acc[mm][nn] = __builtin_amdgcn_mfma_f32_16x16x32_bf16(
                    ah[mm], bfr[nn], acc[mm][nn], 0, 0, 0);
                acc[mm][nn] = __builtin_amdgcn_mfma_f32_16x16x32_bf16(
                    al[mm], bfr[nn], acc[mm][nn], 0, 0, 0);
            }
    }
#pragma unroll
    for (int mm = 0; mm < 2; ++mm)
#pragma unroll
        for (int nn = 0; nn < 8; ++nn) {
            int e  = nBase + wn * 128 + nn * 16 + m16;
            int d1 = wm * 32 + mm * 16 + quad * 4;
            union { bf16_t hh[4]; uint2 u; } pk;
#pragma unroll
            for (int i = 0; i < 4; ++i) pk.hh[i] = (bf16_t)acc[mm][nn][i];
            *(uint2*)(ut + ((size_t)b * 768 + e) * 768 + h * 64 + d1) = pk.u;
        }
}

// ---------------------------------------------------------------------------
// Final GEMM: out = relu(q @ U^b + lin_b) + x (fp32). 256x128 tiles,
// grid (6, 64), 512 thr.
// ---------------------------------------------------------------------------
__global__ __launch_bounds__(512) void gemm_out_kernel(const bf16_t* __restrict__ q,
                                                       const bf16_t* __restrict__ ut,
                                                       const float* __restrict__ linb,
                                                       const float* __restrict__ x,
                                                       float* __restrict__ out) {
    __shared__ bf16_t smem[24576];
    f32x4 acc[4][4];
    const int mBase = blockIdx.y * 256, nBase = blockIdx.x * 128;
    const int b = mBase >> 10;
    gemm_core_256<768>(q, ut + (size_t)b * 768 * 768, mBase, nBase, acc,
                       smem, smem + 16384);

    const int lane = threadIdx.x & 63, wave = threadIdx.x >> 6;
    const int wm = wave >> 1, wn = wave & 1;
    const int m16 = lane & 15, quad = lane >> 4;
#pragma unroll
    for (int mm = 0; mm < 4; ++mm) {
#pragma unroll
        for (int i = 0; i < 4; ++i) {
            size_t row = mBase + wm * 64 + mm * 16 + quad * 4 + i;
#pragma unroll
            for (int nn = 0; nn < 4; ++nn) {
                int col = nBase + wn * 64 + nn * 16 + m16;
                float v = acc[mm][nn][i] + linb[col];
                v = fmaxf(v, 0.f) + x[row * EE + col];
                out[row * EE + col] = v;
            }
        }
    }
}

// ---------------------------------------------------------------------------
// Launch
// ---------------------------------------------------------------------------
extern "C" void kernel_launch(void* const* d_in, const int* in_sizes, int n_in,
                              void* d_out, int out_size, void* d_ws, size_t ws_size,
                              hipStream_t stream) {
    const float* x    = (const float*)d_in[0];
    const float* lnw  = (const float*)d_in[1];
    const float* lnb  = (const float*)d_in[2];
    const float* qkvw = (const float*)d_in[3];
    const float* linw = (const float*)d_in[4];
    const float* linb = (const float*)d_in[5];
    float* out = (float*)d_out;
    char* ws = (char*)d_ws;

    // Workspace layout (bytes), total ~105.4 MB. Rotation:
    //   qkvT dead after gemm_qkv -> thi/tlo ; kt dead after kv -> Ut
    float*  part  = (float*)(ws + 0);          //  8192 B
    float*  stats = (float*)(ws + 8192);       //   128 B
    bf16_t* xn    = (bf16_t*)(ws + 8448);      //  25165824 B
    bf16_t* qkvT  = (bf16_t*)(ws + 25174272);  //   3538944 B
    bf16_t* lwT   = (bf16_t*)(ws + 28713216);  //   1179648 B
    bf16_t* q     = (bf16_t*)(ws + 29892864);  //  25165824 B  (B,P,HID)
    bf16_t* kt    = (bf16_t*)(ws + 55058688);  //  25165824 B
    bf16_t* vt    = (bf16_t*)(ws + 80224512);  //  25165824 B -> end 105390336
    bf16_t* thi   = qkvT;                      // 1572864 B
    bf16_t* tlo   = qkvT + 192 * 4096;         // 1572864 B
    bf16_t* ut    = kt;                        // 18874368 B (kt dead after kv)

    stats1_kernel<<<dim3(BB * 64), dim3(256), 0, stream>>>(x, part);
    prep_kernel<<<dim3(577), dim3(256), 0, stream>>>(qkvw, linw, part, qkvT, lwT, stats);
    ln_apply_kernel<<<dim3(6144), dim3(256), 0, stream>>>(x, lnw, lnb, stats, xn);
    gemm_qkv_kernel<<<dim3(18, 64), dim3(512), 0, stream>>>(xn, qkvT, q, kt, vt);
    kv_kernel<<<dim3(192), dim3(256), 0, stream>>>(kt, vt, thi, tlo);
    u_kernel<<<dim3(192, 3), dim3(256), 0, stream>>>(thi, tlo, lwT, ut);
    gemm_out_kernel<<<dim3(6, 64), dim3(512), 0, stream>>>(q, ut, linb, x, out);
}